// Round 1
// baseline (62.346 us; speedup 1.0000x reference)
//
#include <hip/hip_runtime.h>
#include <hip/hip_bf16.h>

// Problem constants
static constexpr int FEAT_  = 3136;   // K of GEMM1
static constexpr int KSTEPS = 98;     // 3136 / 32
static constexpr int RSTR   = 300;    // x row stride (proposals per batch)
static constexpr int SROWS  = 128;    // SELECTED_PROPOSAL
static constexpr int HID    = 64;     // hidden
static constexpr int NCLS   = 21;     // classes
static constexpr int BM     = 32;     // rows per block

typedef __attribute__((ext_vector_type(8))) short bf16x8;
typedef __attribute__((ext_vector_type(4))) float f32x4;

// W1 pre-packed in MFMA B-fragment order: [kstep][ntile][lane] -> 8 bf16.
// 98*4*64 frags * 16 B = 401,408 B. Module-scope device memory: avoids any
// dependence on ws_size, rewritten deterministically every launch.
__device__ bf16x8 g_w1p[KSTEPS * 4 * 64];

__device__ __forceinline__ short f2bf(float f) {
    union { float f; unsigned u; } v; v.f = f;
    unsigned r = v.u + 0x7fffu + ((v.u >> 16) & 1u);   // round-to-nearest-even
    return (short)(r >> 16);
}

// One thread per B-fragment (8 bf16): t = (ks*4 + nt)*64 + lane
__global__ __launch_bounds__(256) void pack_w1(const float* __restrict__ W1) {
    int t = blockIdx.x * 256 + threadIdx.x;        // 0 .. 25087
    int lane = t & 63;
    int nt   = (t >> 6) & 3;
    int ks   = t >> 8;
    int col  = nt * 16 + (lane & 15);              // B col = lane % 16
    int k0   = ks * 32 + (lane >> 4) * 8;          // B k   = (lane/16)*8 + j
    bf16x8 v;
    #pragma unroll
    for (int j = 0; j < 8; ++j) v[j] = f2bf(W1[(k0 + j) * HID + col]);
    g_w1p[t] = v;
}

__global__ __launch_bounds__(512) void fused_main(
    const float* __restrict__ x,  const float* __restrict__ b1,
    const float* __restrict__ W2, const float* __restrict__ b2,
    const int*  __restrict__ keep, float* __restrict__ out)
{
    __shared__ float h_lds[BM][HID + 1];   // +1 pad: conflict-free writes
    __shared__ float w2s[HID * NCLS];

    const int tid = threadIdx.x;
    // Stage W2 (fp32, 5.25 KB). Synced by the barrier after the K-loop.
    for (int i = tid; i < HID * NCLS; i += 512) w2s[i] = W2[i];

    const int lane  = tid & 63;
    const int wv    = tid >> 6;        // 0..7 waves
    const int mhalf = wv & 1;          // row-half of the 32-row tile
    const int nq    = wv >> 1;         // 16-col quarter of HID
    const int row_base = blockIdx.x * BM;       // flat (b*128 + s) row
    const int b      = row_base >> 7;
    const int s_base = row_base & 127;

    // A-frag: lane supplies row (lane&15), k-chunk (lane>>4)*8 .. +8
    const int s_row = s_base + mhalf * 16 + (lane & 15);
    const float* xp = x + (b * RSTR + s_row) * FEAT_ + ((lane >> 4) * 8);
    const bf16x8* w1p = g_w1p + nq * 64 + lane;   // += 256 per kstep

    f32x4 acc = {0.f, 0.f, 0.f, 0.f};
    #pragma unroll 4
    for (int ks = 0; ks < KSTEPS; ++ks) {
        float4 a0 = *(const float4*)(xp + ks * 32);
        float4 a1 = *(const float4*)(xp + ks * 32 + 4);
        bf16x8 bfv = w1p[ks * 256];
        bf16x8 af;
        af[0] = f2bf(a0.x); af[1] = f2bf(a0.y);
        af[2] = f2bf(a0.z); af[3] = f2bf(a0.w);
        af[4] = f2bf(a1.x); af[5] = f2bf(a1.y);
        af[6] = f2bf(a1.z); af[7] = f2bf(a1.w);
        acc = __builtin_amdgcn_mfma_f32_16x16x32_bf16(af, bfv, acc, 0, 0, 0);
    }

    // D layout (m89): col = lane&15, row = (lane>>4)*4 + reg
    const int colg = nq * 16 + (lane & 15);
    const float b1v = b1[colg];
    #pragma unroll
    for (int r = 0; r < 4; ++r) {
        float v = acc[r] + b1v;
        v = (v >= 0.f) ? v : 0.1f * v;            // leaky relu #1
        h_lds[mhalf * 16 + (lane >> 4) * 4 + r][colg] = v;
    }
    __syncthreads();

    // GEMM2: [32 x 64] @ [64 x 21] + b2, leaky, keep_count mask
    const int limit = min(keep[b], SROWS);
    for (int idx = tid; idx < BM * NCLS; idx += 512) {
        int r = idx / NCLS;
        int c = idx - r * NCLS;
        float a2 = b2[c];
        #pragma unroll 8
        for (int col = 0; col < HID; ++col)
            a2 += h_lds[r][col] * w2s[col * NCLS + c];
        a2 = (a2 >= 0.f) ? a2 : 0.1f * a2;        // leaky relu #2
        out[(row_base + r) * NCLS + c] = (s_base + r < limit) ? a2 : 0.f;
    }
}

extern "C" void kernel_launch(void* const* d_in, const int* in_sizes, int n_in,
                              void* d_out, int out_size, void* d_ws, size_t ws_size,
                              hipStream_t stream) {
    const float* x    = (const float*)d_in[0];
    const float* W1   = (const float*)d_in[1];
    const float* b1   = (const float*)d_in[2];
    const float* W2   = (const float*)d_in[3];
    const float* b2   = (const float*)d_in[4];
    const int*   keep = (const int*)d_in[5];
    float* out = (float*)d_out;

    hipLaunchKernelGGL(pack_w1,   dim3(KSTEPS), dim3(256), 0, stream, W1);
    hipLaunchKernelGGL(fused_main, dim3((64 * SROWS) / BM), dim3(512), 0, stream,
                       x, b1, W2, b2, keep, out);
}

// Round 2
// 31.862 us; speedup vs baseline: 1.9567x; 1.9567x over previous
//
#include <hip/hip_runtime.h>
#include <hip/hip_bf16.h>

// Problem constants
static constexpr int FEAT_  = 3136;   // K of GEMM1
static constexpr int KSTEPS = 98;     // 3136 / 32
static constexpr int RSTR   = 300;    // x row stride (proposals per batch)
static constexpr int SROWS  = 128;    // SELECTED_PROPOSAL
static constexpr int HID    = 64;     // hidden
static constexpr int NCLS   = 21;     // classes

typedef __attribute__((ext_vector_type(8))) short bf16x8;
typedef __attribute__((ext_vector_type(4))) float f32x4;

// W1 pre-packed in MFMA B-fragment order: [kstep][ntile][lane] -> 8 bf16.
__device__ bf16x8 g_w1p[KSTEPS * 4 * 64];

__device__ __forceinline__ short f2bf(float f) {
    union { float f; unsigned u; } v; v.f = f;
    unsigned r = v.u + 0x7fffu + ((v.u >> 16) & 1u);   // round-to-nearest-even
    return (short)(r >> 16);
}

// One thread per B-fragment (8 bf16): t = (ks*4 + nt)*64 + lane
__global__ __launch_bounds__(256) void pack_w1(const float* __restrict__ W1) {
    int t = blockIdx.x * 256 + threadIdx.x;        // 0 .. 25087
    int lane = t & 63;
    int nt   = (t >> 6) & 3;
    int ks   = t >> 8;
    int col  = nt * 16 + (lane & 15);              // B col = lane % 16
    int k0   = ks * 32 + (lane >> 4) * 8;          // B k   = (lane/16)*8 + j
    bf16x8 v;
    #pragma unroll
    for (int j = 0; j < 8; ++j) v[j] = f2bf(W1[(k0 + j) * HID + col]);
    g_w1p[t] = v;
}

// One block = 16 output rows. 4 waves split the K dimension (no redundant
// x reads); each wave computes all 4 hidden-column quarters.
__global__ __launch_bounds__(256) void fused_main(
    const float* __restrict__ x,  const float* __restrict__ b1,
    const float* __restrict__ W2, const float* __restrict__ b2,
    const int*  __restrict__ keep, float* __restrict__ out)
{
    const int tid  = threadIdx.x;
    const int lane = tid & 63;
    const int wv   = tid >> 6;                 // 0..3 (K-split)
    const int row_base = blockIdx.x * 16;      // flat (b*128 + s) row
    const int b      = row_base >> 7;
    const int s_base = row_base & 127;

    float* outp = out + row_base * NCLS;
    const int limit = min(keep[b], SROWS);

    // Whole 16-row group masked out -> just write zeros, skip all loads.
    if (s_base >= limit) {
        for (int i = tid; i < 16 * NCLS; i += 256) outp[i] = 0.f;
        return;
    }

    __shared__ float hp[4][16][HID + 1];   // per-wave partial sums
    __shared__ float hf[16][HID + 2];      // reduced h
    __shared__ float w2s[HID * NCLS];

    for (int i = tid; i < HID * NCLS; i += 256) w2s[i] = W2[i];

    // K-range for this wave: [ks0, ks1)
    const int ks0 = (wv * KSTEPS) >> 2;
    const int ks1 = ((wv + 1) * KSTEPS) >> 2;

    // A-frag: lane supplies row (lane&15), k-chunk (lane>>4)*8
    const int s_row = s_base + (lane & 15);
    const float* xp = x + (b * RSTR + s_row) * FEAT_ + ((lane >> 4) * 8);
    const bf16x8* wp = g_w1p + lane;           // frag (ks*4+nq)*64 + lane

    f32x4 acc0 = {0.f,0.f,0.f,0.f}, acc1 = {0.f,0.f,0.f,0.f};
    f32x4 acc2 = {0.f,0.f,0.f,0.f}, acc3 = {0.f,0.f,0.f,0.f};

    #pragma unroll 2
    for (int ks = ks0; ks < ks1; ++ks) {
        float4 a0 = *(const float4*)(xp + ks * 32);
        float4 a1 = *(const float4*)(xp + ks * 32 + 4);
        bf16x8 bv0 = wp[(ks * 4 + 0) * 64];
        bf16x8 bv1 = wp[(ks * 4 + 1) * 64];
        bf16x8 bv2 = wp[(ks * 4 + 2) * 64];
        bf16x8 bv3 = wp[(ks * 4 + 3) * 64];
        bf16x8 af;
        af[0] = f2bf(a0.x); af[1] = f2bf(a0.y);
        af[2] = f2bf(a0.z); af[3] = f2bf(a0.w);
        af[4] = f2bf(a1.x); af[5] = f2bf(a1.y);
        af[6] = f2bf(a1.z); af[7] = f2bf(a1.w);
        acc0 = __builtin_amdgcn_mfma_f32_16x16x32_bf16(af, bv0, acc0, 0, 0, 0);
        acc1 = __builtin_amdgcn_mfma_f32_16x16x32_bf16(af, bv1, acc1, 0, 0, 0);
        acc2 = __builtin_amdgcn_mfma_f32_16x16x32_bf16(af, bv2, acc2, 0, 0, 0);
        acc3 = __builtin_amdgcn_mfma_f32_16x16x32_bf16(af, bv3, acc3, 0, 0, 0);
    }

    // D layout: col = lane&15 (+16*nq), row = (lane>>4)*4 + r
    const int r0 = (lane >> 4) * 4;
    const int c0 = lane & 15;
    #pragma unroll
    for (int r = 0; r < 4; ++r) {
        hp[wv][r0 + r][c0     ] = acc0[r];
        hp[wv][r0 + r][c0 + 16] = acc1[r];
        hp[wv][r0 + r][c0 + 32] = acc2[r];
        hp[wv][r0 + r][c0 + 48] = acc3[r];
    }
    __syncthreads();

    // Reduce over the 4 K-partials, add b1, leaky relu #1
    for (int e = tid; e < 16 * HID; e += 256) {
        int row = e >> 6, col = e & 63;
        float v = hp[0][row][col] + hp[1][row][col]
                + hp[2][row][col] + hp[3][row][col] + b1[col];
        hf[row][col] = (v >= 0.f) ? v : 0.1f * v;
    }
    __syncthreads();

    // GEMM2: [16 x 64] @ [64 x 21] + b2, leaky, keep_count mask
    for (int idx = tid; idx < 16 * NCLS; idx += 256) {
        int r = idx / NCLS;
        int c = idx - r * NCLS;
        float a2 = b2[c];
        #pragma unroll 8
        for (int col = 0; col < HID; ++col)
            a2 += hf[r][col] * w2s[col * NCLS + c];
        a2 = (a2 >= 0.f) ? a2 : 0.1f * a2;        // leaky relu #2
        outp[idx] = (s_base + r < limit) ? a2 : 0.f;
    }
}

extern "C" void kernel_launch(void* const* d_in, const int* in_sizes, int n_in,
                              void* d_out, int out_size, void* d_ws, size_t ws_size,
                              hipStream_t stream) {
    const float* x    = (const float*)d_in[0];
    const float* W1   = (const float*)d_in[1];
    const float* b1   = (const float*)d_in[2];
    const float* W2   = (const float*)d_in[3];
    const float* b2   = (const float*)d_in[4];
    const int*   keep = (const int*)d_in[5];
    float* out = (float*)d_out;

    hipLaunchKernelGGL(pack_w1,    dim3(KSTEPS), dim3(256), 0, stream, W1);
    hipLaunchKernelGGL(fused_main, dim3((64 * SROWS) / 16), dim3(256), 0, stream,
                       x, b1, W2, b2, keep, out);
}